// Round 3
// baseline (1380.120 us; speedup 1.0000x reference)
//
#include <hip/hip_runtime.h>
#include <hip/hip_cooperative_groups.h>
#include <float.h>

namespace cg = cooperative_groups;

// GenerativeUpsample BCE get_keep + prune.
// Inputs: fea (N,64) f32, pred_f (N,1) f32, batch_ids (N,) i32 sorted,
//         target_points_num (8,) i32.
// Outputs (concat): pruned_fea (N*64) f32, keep (N,) written as 0/1 f32.
//
// Exact per-batch kth-smallest via 4-round 8-bit MSD radix select on the
// monotonic uint transform of the float bits, fused with the prune pass.
//
// R3 changes vs R2 (908 us; ~216 us controllable after 2x346 us harness fills):
//  - Single cooperative kernel (1024x256, 4 blocks/CU). Keys+batch-ids loaded
//    ONCE into registers (8/thread, statically indexed); all 4 radix rounds run
//    from registers -> removes 3x 17 MB pred/bids re-reads and 8 kernel
//    launches, replaced by 5 grid.sync().
//  - Scans done redundantly in every block (wave __shfl_up prefix over 256
//    bins) so results need no broadcast sync; all select state lives in LDS.
//  - Prune fused: per sub-iteration a block owns 256 contiguous rows; keep
//    flags shared via LDS so the row copy is fully coalesced; nontemporal
//    loads/stores; compare entirely in key space.
//  - Host-side fallback to the R2 multi-kernel path if cooperative launch is
//    unavailable or n > 1024*256*8.

#define BATCHES 8
#define NBLK 1024
#define NTHR 256
#define NTOT (NBLK * NTHR)   // 262144 threads
#define MAXE 8               // supports n <= 2,097,152
#define NEG_FLT_MAX_KEY 0x00800000u  // f2key(-FLT_MAX)

typedef float f32x4 __attribute__((ext_vector_type(4)));

__device__ __forceinline__ unsigned f2key(float x) {
    unsigned u = __float_as_uint(x);
    return (u & 0x80000000u) ? ~u : (u | 0x80000000u);
}
__device__ __forceinline__ float key2f(unsigned k) {
    unsigned u = (k & 0x80000000u) ? (k & 0x7FFFFFFFu) : ~k;
    return __uint_as_float(u);
}

// Cross-block state (device-scope atomics only). Zeroed at the start of each
// fused call; fallback path zeroes it explicitly with a tiny kernel.
__device__ unsigned g_hist[4 * BATCHES * 256];  // [round][batch][bin]
__device__ unsigned g_remk[BATCHES];
__device__ unsigned g_prefix[BATCHES];
__device__ unsigned g_active[BATCHES];
__device__ float    g_thresh[BATCHES];

// ============================ fused cooperative path ========================

__global__ __launch_bounds__(NTHR, 4) void fused_kernel(
        const float* __restrict__ fea,
        const float* __restrict__ pred,
        const int* __restrict__ bids,
        const int* __restrict__ target,
        float* __restrict__ out,
        int n) {
    cg::grid_group grid = cg::this_grid();
    __shared__ unsigned lh[BATCHES * 256];
    __shared__ unsigned lpre[BATCHES];
    __shared__ unsigned lremk[BATCHES];
    __shared__ unsigned lact[BATCHES];
    __shared__ unsigned lthreshk[BATCHES];
    __shared__ float    skeep[NTHR];

    const int t = threadIdx.x;
    const int tid = blockIdx.x * NTHR + t;

    // Block 0 zeroes the global hists (self-clean invariant does not survive
    // the redundant-scan design, so zero at entry) while all blocks zero LDS.
    if (blockIdx.x == 0) {
        for (int i = t; i < 4 * BATCHES * 256; i += NTHR) g_hist[i] = 0u;
    }
    for (int i = t; i < BATCHES * 256; i += NTHR) lh[i] = 0u;
    __syncthreads();

    // Load keys + batch ids into registers (statically indexed), build round-0
    // LDS hist on the way.
    unsigned key[MAXE];
    unsigned bn = 0u;  // 8 batch ids, 4 bits each; 8 = invalid (tail)
    #pragma unroll
    for (int i = 0; i < MAXE; i++) {
        int idx = tid + i * NTOT;
        unsigned k = 0u, b = 8u;
        if (idx < n) {
            k = f2key(pred[idx]);
            b = (unsigned)bids[idx];
            atomicAdd(&lh[b * 256 + (k >> 24)], 1u);
        }
        key[i] = k;
        bn |= (b << (4 * i));
    }
    __syncthreads();
    grid.sync();  // g_hist zeroing complete

    // Flush round-0 hist to global, zero LDS copy behind the read.
    for (int i = t; i < BATCHES * 256; i += NTHR) {
        unsigned v = lh[i];
        if (v) atomicAdd(&g_hist[i], v);
        lh[i] = 0u;
    }
    grid.sync();  // round-0 flush complete

    #pragma unroll
    for (int p = 0; p < 4; p++) {
        // ---- scan round p (redundant in every block; wave-level prefix).
        // wave w handles batches w and w+4.
        {
            int lane = t & 63;
            int w = t >> 6;
            for (int bb = 0; bb < 2; bb++) {
                int b = w + bb * 4;
                if (p > 0 && lact[b] == 0u) {
                    if (p == 3 && lane == 0) lthreshk[b] = NEG_FLT_MAX_KEY;
                    continue;
                }
                const unsigned* h = g_hist + (p * BATCHES + b) * 256;
                unsigned c0 = h[lane * 4 + 0], c1 = h[lane * 4 + 1];
                unsigned c2 = h[lane * 4 + 2], c3 = h[lane * 4 + 3];
                unsigned lt = c0 + c1 + c2 + c3;
                unsigned sc = lt;
                #pragma unroll
                for (int off = 1; off < 64; off <<= 1) {
                    unsigned u = __shfl_up(sc, off);
                    if (lane >= off) sc += u;
                }
                unsigned total = __shfl(sc, 63);
                unsigned r;
                if (p == 0) {
                    int tg = target[b];
                    bool act = ((int)total > tg);
                    if (lane == 0) lact[b] = act ? 1u : 0u;
                    if (!act) continue;  // wave-uniform
                    r = total - (unsigned)tg - 1u;  // 0-indexed rank
                } else {
                    r = lremk[b];  // all lanes read before winner writes
                }
                unsigned excl = sc - lt;
                if (r >= excl && r < sc) {  // unique winner lane
                    unsigned rr = r - excl;
                    unsigned bin, cum;
                    if (rr < c0)                { bin = 0u; cum = 0u; }
                    else if (rr < c0 + c1)      { bin = 1u; cum = c0; }
                    else if (rr < c0 + c1 + c2) { bin = 2u; cum = c0 + c1; }
                    else                        { bin = 3u; cum = c0 + c1 + c2; }
                    unsigned binidx = (unsigned)(lane * 4) + bin;
                    unsigned np = (p == 0) ? binidx : ((lpre[b] << 8) | binidx);
                    lpre[b] = np;
                    lremk[b] = rr - cum;
                    if (p == 3) lthreshk[b] = np;
                }
            }
        }
        __syncthreads();  // scan results visible block-wide

        if (p == 3) break;

        // ---- build round p+1 hist from registers (prefix filter)
        const int shiftHi  = 24 - 8 * p;  // prefix length p+1 bytes
        const int shiftBin = 16 - 8 * p;
        #pragma unroll
        for (int i = 0; i < MAXE; i++) {
            unsigned b = (bn >> (4 * i)) & 0xFu;
            if (b < 8u && lact[b]) {
                unsigned k = key[i];
                if ((k >> shiftHi) == lpre[b])
                    atomicAdd(&lh[b * 256 + ((k >> shiftBin) & 0xFFu)], 1u);
            }
        }
        __syncthreads();
        unsigned* gh = g_hist + (p + 1) * BATCHES * 256;
        for (int i = t; i < BATCHES * 256; i += NTHR) {
            unsigned v = lh[i];
            if (v) atomicAdd(&gh[i], v);
            lh[i] = 0u;
        }
        grid.sync();  // round p+1 flush complete
    }

    // ---- fused prune. Per sub-iteration i this block owns 256 contiguous
    // rows [rowbase, rowbase+256); keep flags via LDS keep the 64 KB row copy
    // fully coalesced. Key-space compare (strict >) matches reference.
    #pragma unroll
    for (int i = 0; i < MAXE; i++) {
        int rowbase = blockIdx.x * NTHR + i * NTOT;
        int idx = rowbase + t;
        unsigned b = (bn >> (4 * i)) & 0xFu;
        bool kp = (idx < n) && (b < 8u) && (key[i] > lthreshk[b]);
        skeep[t] = kp ? 1.0f : 0.0f;
        __syncthreads();
        if (rowbase < n) {
            int rows = min(NTHR, n - rowbase);
            const f32x4* src = (const f32x4*)fea + (size_t)rowbase * 16;
            f32x4* dst = (f32x4*)out + (size_t)rowbase * 16;
            for (int f = t; f < rows * 16; f += NTHR) {
                int rl = f >> 4;
                f32x4 v = {0.f, 0.f, 0.f, 0.f};
                if (skeep[rl] > 0.5f) v = __builtin_nontemporal_load(src + f);
                __builtin_nontemporal_store(v, dst + f);
            }
            if (idx < n)
                __builtin_nontemporal_store(skeep[t], out + (size_t)n * 64 + idx);
        }
        __syncthreads();  // before skeep overwrite
    }
}

// ============================ fallback path (R2) ============================

__global__ void zero_hist_kernel() {
    int i = blockIdx.x * blockDim.x + threadIdx.x;
    if (i < 4 * BATCHES * 256) g_hist[i] = 0u;
}

__global__ __launch_bounds__(256) void hist0_kernel(const float* __restrict__ pred,
                                                    const int* __restrict__ bids,
                                                    int n) {
    __shared__ unsigned lh[BATCHES * 256];
    for (int i = threadIdx.x; i < BATCHES * 256; i += 256) lh[i] = 0u;
    __syncthreads();
    int stride = gridDim.x * blockDim.x;
    for (int i = blockIdx.x * blockDim.x + threadIdx.x; i < n; i += stride) {
        int b = bids[i];
        unsigned k = f2key(pred[i]);
        atomicAdd(&lh[b * 256 + (k >> 24)], 1u);
    }
    __syncthreads();
    for (int i = threadIdx.x; i < BATCHES * 256; i += 256) {
        unsigned v = lh[i];
        if (v) atomicAdd(&g_hist[i], v);
    }
}

__global__ __launch_bounds__(256) void histN_kernel(const float* __restrict__ pred,
                                                    const int* __restrict__ bids,
                                                    int n, int shiftHi, int shiftBin,
                                                    int pass) {
    __shared__ unsigned lh[BATCHES * 256];
    __shared__ unsigned lpre[BATCHES];
    __shared__ unsigned lact[BATCHES];
    for (int i = threadIdx.x; i < BATCHES * 256; i += 256) lh[i] = 0u;
    if (threadIdx.x < BATCHES) {
        lpre[threadIdx.x] = g_prefix[threadIdx.x];
        lact[threadIdx.x] = g_active[threadIdx.x];
    }
    __syncthreads();
    int stride = gridDim.x * blockDim.x;
    for (int i = blockIdx.x * blockDim.x + threadIdx.x; i < n; i += stride) {
        int b = bids[i];
        if (!lact[b]) continue;
        unsigned k = f2key(pred[i]);
        if ((k >> shiftHi) == lpre[b])
            atomicAdd(&lh[b * 256 + ((k >> shiftBin) & 0xFFu)], 1u);
    }
    __syncthreads();
    unsigned* gh = g_hist + pass * BATCHES * 256;
    for (int i = threadIdx.x; i < BATCHES * 256; i += 256) {
        unsigned v = lh[i];
        if (v) atomicAdd(&gh[i], v);
    }
}

__global__ __launch_bounds__(256) void scan_kernel(const int* __restrict__ target,
                                                   int pass) {
    int b = blockIdx.x;
    int t = threadIdx.x;
    unsigned* h = g_hist + (pass * BATCHES + b) * 256;
    unsigned c = h[t];
    h[t] = 0u;
    if (pass > 0 && !g_active[b]) {
        if (pass == 3 && t == 0) g_thresh[b] = -FLT_MAX;
        return;
    }
    __shared__ unsigned s[256];
    s[t] = c;
    __syncthreads();
    for (int off = 1; off < 256; off <<= 1) {
        unsigned v = s[t];
        unsigned a = (t >= off) ? s[t - off] : 0u;
        __syncthreads();
        s[t] = v + a;
        __syncthreads();
    }
    unsigned incl = s[t];
    unsigned total = s[255];
    unsigned r;
    if (pass == 0) {
        int tg = target[b];
        bool act = ((int)total > tg) && (total > 0u);
        if (t == 0) g_active[b] = act ? 1u : 0u;
        if (!act) return;
        r = total - (unsigned)tg - 1u;
    } else {
        r = g_remk[b];
    }
    __syncthreads();
    unsigned excl = incl - c;
    if (c > 0u && excl <= r && r < incl) {
        unsigned p = (pass == 0) ? (unsigned)t : ((g_prefix[b] << 8) | (unsigned)t);
        g_prefix[b] = p;
        g_remk[b] = r - excl;
        if (pass == 3) g_thresh[b] = key2f(p);
    }
}

__global__ __launch_bounds__(256) void prune_kernel(const float* __restrict__ fea,
                                                    const float* __restrict__ pred,
                                                    const int* __restrict__ bids,
                                                    float* __restrict__ out,
                                                    int n) {
    __shared__ float sth[BATCHES];
    if (threadIdx.x < BATCHES) sth[threadIdx.x] = g_thresh[threadIdx.x];
    __syncthreads();
    long total4 = (long)n * 16;
    long stride = (long)gridDim.x * blockDim.x;
    for (long idx = (long)blockIdx.x * blockDim.x + threadIdx.x; idx < total4;
         idx += stride) {
        int row = (int)(idx >> 4);
        int l = (int)(idx & 15);
        int b = bids[row];
        bool kp = pred[row] > sth[b];
        f32x4 v = {0.f, 0.f, 0.f, 0.f};
        if (kp) v = __builtin_nontemporal_load((const f32x4*)fea + idx);
        __builtin_nontemporal_store(v, (f32x4*)out + idx);
        if (l == 0)
            __builtin_nontemporal_store(kp ? 1.0f : 0.0f, out + (size_t)n * 64 + row);
    }
}

// ================================ launcher ==================================

extern "C" void kernel_launch(void* const* d_in, const int* in_sizes, int n_in,
                              void* d_out, int out_size, void* d_ws, size_t ws_size,
                              hipStream_t stream) {
    (void)d_ws; (void)ws_size; (void)n_in; (void)out_size;
    const float* fea    = (const float*)d_in[0];
    const float* pred   = (const float*)d_in[1];
    const int*   bids   = (const int*)d_in[2];
    const int*   target = (const int*)d_in[3];
    float* out = (float*)d_out;
    int n = in_sizes[1];  // pred_f element count = N

    hipError_t e = hipErrorUnknown;
    if (n <= NTOT * MAXE) {
        void* args[] = {(void*)&fea, (void*)&pred, (void*)&bids,
                        (void*)&target, (void*)&out, (void*)&n};
        e = hipLaunchCooperativeKernel(reinterpret_cast<void*>(fused_kernel),
                                       dim3(NBLK), dim3(NTHR), args, 0, stream);
    }
    if (e != hipSuccess) {
        // Fallback: R2 multi-kernel path (robust to any n / no coop support).
        zero_hist_kernel<<<32, 256, 0, stream>>>();
        hist0_kernel<<<1024, 256, 0, stream>>>(pred, bids, n);
        scan_kernel<<<BATCHES, 256, 0, stream>>>(target, 0);
        for (int p = 1; p <= 3; p++) {
            int shiftHi = 32 - 8 * p;
            int shiftBin = 24 - 8 * p;
            histN_kernel<<<2048, 256, 0, stream>>>(pred, bids, n, shiftHi, shiftBin, p);
            scan_kernel<<<BATCHES, 256, 0, stream>>>(target, p);
        }
        prune_kernel<<<8192, 256, 0, stream>>>(fea, pred, bids, out, n);
    }
}